// Round 6
// baseline (294.289 us; speedup 1.0000x reference)
//
#include <hip/hip_runtime.h>
#include <hip/hip_bf16.h>

// QuantizedLinear: out[n][o] = scale[o] * dot(x[n,:], (q[o,:]-8)) + bias[o]
// R6 = R5 + true double-buffered K-loop (one barrier per tile, 2x-unrolled,
// four distinct static LDS arrays so ds_read(buf0) has no false dependency
// on in-flight global_load_lds(buf1)). Each barrier's structural vmcnt(0)
// drain now waits on staging issued one FULL compute phase (32 MFMA) earlier
// -> stall ~0. Cost: 64KB LDS = 2 blocks/CU (the experiment: pipelining vs
// occupancy; m99/m100 were neutral on the CONFLICTED m97 — ours is clean).
// Kept from R5: compile-time K/N, XCD 4x2 supertile swizzle, row-major LDS
// + XOR swizzle (conflicts=0), hoisted immediate fragment addrs, 16x16x32
// bf16 MFMA, fused scale/bias epilogue. Revert condition: gemm >= 155us.

typedef __attribute__((ext_vector_type(8))) __bf16 bf16x8;
typedef __attribute__((ext_vector_type(4))) float f32x4;

#define GLOBAL_AS __attribute__((address_space(1)))
#define LDS_AS __attribute__((address_space(3)))

#define BM 128
#define BN 128
#define BK 64

__device__ inline unsigned short f32_to_bf16(float f) {
    unsigned int u = __float_as_uint(f);
    unsigned int r = (u + 0x7FFFu + ((u >> 16) & 1u)) >> 16;
    return (unsigned short)r;
}

// ---- merged preprocessing: x fp32 -> bf16 AND packed nibbles -> bf16 ints ----
__global__ void prep(const float* __restrict__ x, unsigned short* __restrict__ xb,
                     const int* __restrict__ wp, unsigned short* __restrict__ wb,
                     int n8x, int n4w) {
    const int stride = gridDim.x * blockDim.x;
    const int total = n8x + n4w;
    for (int i = blockIdx.x * blockDim.x + threadIdx.x; i < total; i += stride) {
        if (i < n8x) {
            float4 a = ((const float4*)x)[2 * i];
            float4 b = ((const float4*)x)[2 * i + 1];
            union { unsigned short h[8]; uint4 u; } o;
            o.h[0] = f32_to_bf16(a.x); o.h[1] = f32_to_bf16(a.y);
            o.h[2] = f32_to_bf16(a.z); o.h[3] = f32_to_bf16(a.w);
            o.h[4] = f32_to_bf16(b.x); o.h[5] = f32_to_bf16(b.y);
            o.h[6] = f32_to_bf16(b.z); o.h[7] = f32_to_bf16(b.w);
            ((uint4*)xb)[i] = o.u;
        } else {
            int k = i - n8x;
            int4 v = ((const int4*)wp)[k];
            int vals[4] = {v.x, v.y, v.z, v.w};
            union { unsigned short h[8]; uint4 u; } o;
#pragma unroll
            for (int t = 0; t < 4; ++t) {
                o.h[2 * t]     = f32_to_bf16((float)((vals[t] & 0xF) - 8));
                o.h[2 * t + 1] = f32_to_bf16((float)(((vals[t] >> 4) & 0xF) - 8));
            }
            ((uint4*)wb)[k] = o.u;
        }
    }
}

// ---- main GEMM: C[m][n] = sum_k A[m][k]*B[n][k]; epilogue scale/bias ----
// Requires K % (2*BK) == 0 (guarded at launch: K=4096).
template<int K, int N>
__global__ __launch_bounds__(256) void gemm_bt(
    const unsigned short* __restrict__ A,
    const unsigned short* __restrict__ B,
    const float* __restrict__ scales,
    const float* __restrict__ bias,
    float* __restrict__ C,
    int GX)
{
    __shared__ unsigned short As0[BM * BK];  // 16 KB each, 64 KB total
    __shared__ unsigned short Bs0[BN * BK];
    __shared__ unsigned short As1[BM * BK];
    __shared__ unsigned short Bs1[BN * BK];

    const int tid  = threadIdx.x;
    const int wave = tid >> 6;
    const int lane = tid & 63;
    const int wm = wave >> 1;
    const int wn = wave & 1;

    // XCD-aware supertile swizzle: groups of 8 ids -> 4x2 (x,y) tile.
    const int bid = blockIdx.x;
    const int g   = bid >> 3;
    const int t8  = bid & 7;
    const int sgx = GX >> 2;
    const int bx  = (g % sgx) * 4 + (t8 & 3);
    const int by  = (g / sgx) * 2 + (t8 >> 2);
    const int m0 = by * BM;
    const int n0 = bx * BN;

    f32x4 acc[4][4];
#pragma unroll
    for (int i = 0; i < 4; ++i)
#pragma unroll
        for (int j = 0; j < 4; ++j)
            acc[i][j] = (f32x4){0.f, 0.f, 0.f, 0.f};

    // staging: thread tid loads 16B to LDS slot (row=tid>>3 (+32j), kb=tid&7);
    // XOR swizzle: slot holds global k-block kb ^ (row&7).
    const int srow = tid >> 3;
    const int scol = ((tid & 7) ^ (srow & 7)) * 8;

    const unsigned short* Ag = A + (size_t)(m0 + srow) * K + scol;
    const unsigned short* Bg = B + (size_t)(n0 + srow) * K + scol;

    // fragment addressing (hoisted): lane reads row am at swizzled chunk
    // (aq ^ (am&7)); kk=32 is byte-offset ^64.
    const int am = lane & 15;
    const int aq = lane >> 4;
    const int cbyte = ((aq ^ (am & 7)) << 4);

    int aoffB[4], boffB[4];
#pragma unroll
    for (int i = 0; i < 4; ++i)
        aoffB[i] = (wm * 64 + i * 16 + am) * (BK * 2) + cbyte;
#pragma unroll
    for (int j = 0; j < 4; ++j)
        boffB[j] = (wn * 64 + j * 16 + am) * (BK * 2) + cbyte;

#define STAGE(koff, AsD, BsD) do {                                            \
    _Pragma("unroll")                                                         \
    for (int j_ = 0; j_ < 4; ++j_)                                            \
        __builtin_amdgcn_global_load_lds(                                     \
            (const GLOBAL_AS void*)(Ag + (size_t)(j_ * 32) * K + (koff)),     \
            (LDS_AS void*)((AsD) + tid * 8 + j_ * 2048), 16, 0, 0);           \
    _Pragma("unroll")                                                         \
    for (int j_ = 0; j_ < 4; ++j_)                                            \
        __builtin_amdgcn_global_load_lds(                                     \
            (const GLOBAL_AS void*)(Bg + (size_t)(j_ * 32) * K + (koff)),     \
            (LDS_AS void*)((BsD) + tid * 8 + j_ * 2048), 16, 0, 0);           \
} while (0)

#define COMPUTE(AsD, BsD) do {                                                \
    const char* AsB_ = (const char*)(AsD);                                    \
    const char* BsB_ = (const char*)(BsD);                                    \
    {   bf16x8 af[4], bfr[4];                                                 \
        _Pragma("unroll")                                                     \
        for (int i_ = 0; i_ < 4; ++i_) af[i_]  = *(const bf16x8*)(AsB_ + aoffB[i_]); \
        _Pragma("unroll")                                                     \
        for (int j_ = 0; j_ < 4; ++j_) bfr[j_] = *(const bf16x8*)(BsB_ + boffB[j_]); \
        _Pragma("unroll")                                                     \
        for (int i_ = 0; i_ < 4; ++i_)                                        \
            _Pragma("unroll")                                                 \
            for (int j_ = 0; j_ < 4; ++j_)                                    \
                acc[i_][j_] = __builtin_amdgcn_mfma_f32_16x16x32_bf16(af[i_], bfr[j_], acc[i_][j_], 0, 0, 0); \
    }                                                                         \
    {   bf16x8 af[4], bfr[4];                                                 \
        _Pragma("unroll")                                                     \
        for (int i_ = 0; i_ < 4; ++i_) af[i_]  = *(const bf16x8*)(AsB_ + (aoffB[i_] ^ 64)); \
        _Pragma("unroll")                                                     \
        for (int j_ = 0; j_ < 4; ++j_) bfr[j_] = *(const bf16x8*)(BsB_ + (boffB[j_] ^ 64)); \
        _Pragma("unroll")                                                     \
        for (int i_ = 0; i_ < 4; ++i_)                                        \
            _Pragma("unroll")                                                 \
            for (int j_ = 0; j_ < 4; ++j_)                                    \
                acc[i_][j_] = __builtin_amdgcn_mfma_f32_16x16x32_bf16(af[i_], bfr[j_], acc[i_][j_], 0, 0, 0); \
    }                                                                         \
} while (0)

    // Pipelined 2x-unrolled K-loop: one barrier per tile; every barrier's
    // vmcnt(0) drain waits on loads issued one full compute phase earlier.
    STAGE(0, As0, Bs0);
    for (int k0 = 0; k0 < K; k0 += 2 * BK) {
        __syncthreads();                       // drains STAGE(k0) [far slack]
        STAGE(k0 + BK, As1, Bs1);              // k0+BK <= K-BK always (K%128==0)
        COMPUTE(As0, Bs0);
        __syncthreads();                       // drains STAGE(k0+BK) [far slack]
        if (k0 + 2 * BK < K) STAGE(k0 + 2 * BK, As0, Bs0);
        COMPUTE(As1, Bs1);
    }

#undef STAGE
#undef COMPUTE

    // epilogue: C/D layout col=lane&15, row=(lane>>4)*4+reg
    const int cq = lane >> 4;
    const int cc = lane & 15;
#pragma unroll
    for (int j = 0; j < 4; ++j) {
        const int col = n0 + wn * 64 + j * 16 + cc;
        const float s = scales[col];
        const float b = bias[col];
#pragma unroll
        for (int i = 0; i < 4; ++i) {
            const int rowb = m0 + wm * 64 + i * 16 + cq * 4;
#pragma unroll
            for (int r = 0; r < 4; ++r) {
                C[(size_t)(rowb + r) * N + col] = acc[i][j][r] * s + b;
            }
        }
    }
}

// ---- correctness fallback for unexpected shapes ----
__global__ void naive_kernel(const float* __restrict__ x, const int* __restrict__ wp,
                             const float* __restrict__ sc, const float* __restrict__ bs,
                             float* __restrict__ out, int NR, int OUTF, int INF) {
    int idx = blockIdx.x * 256 + threadIdx.x;
    if (idx >= NR * OUTF) return;
    int n = idx / OUTF, o = idx - n * OUTF;
    const float* xr = x + (size_t)n * INF;
    const int* wr = wp + (size_t)o * (INF / 2);
    float acc = 0.f;
    for (int c = 0; c < INF / 2; ++c) {
        int v = wr[c];
        acc += xr[2 * c] * (float)((v & 0xF) - 8) + xr[2 * c + 1] * (float)(((v >> 4) & 0xF) - 8);
    }
    out[idx] = acc * sc[o] + bs[o];
}

extern "C" void kernel_launch(void* const* d_in, const int* in_sizes, int n_in,
                              void* d_out, int out_size, void* d_ws, size_t ws_size,
                              hipStream_t stream) {
    const float* x      = (const float*)d_in[0];
    const int*   wp     = (const int*)d_in[1];
    const float* scales = (const float*)d_in[2];
    const float* bias   = (const float*)d_in[3];
    float* out = (float*)d_out;

    const int OUTF = in_sizes[2];
    const int INF  = (2 * in_sizes[1]) / OUTF;
    const int NR   = in_sizes[0] / INF;

    unsigned short* xb = (unsigned short*)d_ws;
    unsigned short* wb = xb + (size_t)NR * INF;
    const size_t need = ((size_t)NR * INF + (size_t)OUTF * INF) * sizeof(unsigned short);

    if (ws_size >= need && INF == 4096 && OUTF == 4096 && (NR % BM) == 0
        && (in_sizes[0] % 8) == 0 && (in_sizes[1] % 4) == 0) {
        prep<<<2048, 256, 0, stream>>>(x, xb, wp, wb, in_sizes[0] / 8, in_sizes[1] / 4);
        const int GX = OUTF / BN;           // 32
        const int GY = NR / BM;
        gemm_bt<4096, 4096><<<GX * GY, 256, 0, stream>>>(xb, wb, scales, bias, out, GX);
    } else {
        int total = NR * OUTF;
        naive_kernel<<<(total + 255) / 256, 256, 0, stream>>>(x, wp, scales, bias, out, NR, OUTF, INF);
    }
}